// Round 6
// baseline (718.679 us; speedup 1.0000x reference)
//
#include <hip/hip_runtime.h>
#include <hip/hip_bf16.h>
#include <math.h>

typedef __hip_bfloat16 bf16;
typedef __attribute__((ext_vector_type(8))) short s8v;   // 8 bf16 = 4 VGPR (MFMA A/B frag)
typedef __attribute__((ext_vector_type(4))) float f4v;   // MFMA C/D frag

// B=256, S=32, D=512, HW=196
#define BB 256
#define SS 32
#define DD 512
#define HWN 196
#define AP 40   // LDS row pitch (bf16): 80 B -> conflict-free b128 frag reads

__device__ __forceinline__ float b2f(bf16 x){ return __bfloat162float(x); }
__device__ __forceinline__ bf16 f2b(float x){ return __float2bfloat16(x); }
__device__ __forceinline__ float us2f(unsigned short u){
    union { unsigned int i; float f; } t; t.i = ((unsigned int)u) << 16; return t.f;
}
// DT: 1 = inputs are bf16, 0 = inputs are fp32
template<int DT>
__device__ __forceinline__ float ldin(const void* p, size_t i){
    return DT ? b2f(((const bf16*)p)[i]) : ((const float*)p)[i];
}

// ---------------- dtype detector ----------------
__global__ void detect_k(const void* q, int* flag){
    __shared__ int cnt;
    if (threadIdx.x == 0) cnt = 0;
    __syncthreads();
    const unsigned short* u = (const unsigned short*)q;
    unsigned short v = u[threadIdx.x * 4];
    int e = (v >> 7) & 0xFF;
    atomicAdd(&cnt, (e >= 100 && e <= 140) ? 1 : 0);
    __syncthreads();
    if (threadIdx.x == 0) *flag = (cnt > 128) ? 1 : 0;
}

// ---------------- fused weight prep ----------------
struct PJob { const void* s; const void* s2; bf16* d; int R, C, ldd, kofs, mode, nblk, boff; };
struct PrepP { PJob j[11]; const void* war; const void* bk; float* warf; float* bkf; };

template<int DT>
__global__ __launch_bounds__(256) void prep_k(PrepP P, const int* __restrict__ flag){
    if (*flag != DT) return;
    __shared__ float T[32][33];
    int bx = blockIdx.x;
    int ji = 0;
    #pragma unroll
    for (int i = 0; i < 11; ++i) if (bx >= P.j[i].boff) ji = i;
    PJob jb = P.j[ji];
    int t = bx - jb.boff;
    int tx = threadIdx.x & 31, ty = threadIdx.x >> 5;
    if (jb.mode == 3){
        for (int i = threadIdx.x; i < DD; i += 256){
            P.warf[i] = ldin<DT>(P.war, i);
            P.bkf[i]  = ldin<DT>(P.bk, i);
        }
        return;
    }
    int nrt = jb.R >> 5;
    int r0 = (t % nrt) << 5, c0 = (t / nrt) << 5;
    if (jb.mode == 2){
        for (int rr = ty; rr < 32; rr += 8)
            jb.d[(size_t)(r0 + rr) * jb.ldd + jb.kofs + c0 + tx] =
                f2b(ldin<DT>(jb.s, (size_t)(r0 + rr) * jb.C + c0 + tx));
        return;
    }
    for (int rr = ty; rr < 32; rr += 8){
        float v = ldin<DT>(jb.s, (size_t)(r0 + rr) * jb.C + c0 + tx);
        if (jb.mode == 1) v += ldin<DT>(jb.s2, (size_t)(r0 + rr) * jb.C + c0 + tx);
        T[rr][tx] = v;
    }
    __syncthreads();
    for (int rr = ty; rr < 32; rr += 8)
        jb.d[(size_t)(c0 + rr) * jb.ldd + jb.kofs + r0 + tx] = f2b(T[tx][rr]);
}

// ---------------- know transpose (per chunk) ----------------
template<int DT>
__global__ void tr_know(const void* __restrict__ know, bf16* __restrict__ knowT, int b0,
                        const int* __restrict__ flag){
    if (*flag != DT) return;
    int bl = blockIdx.z, b = b0 + bl;
    int n0 = blockIdx.x * 32, g0 = blockIdx.y * 32;
    __shared__ float T[32][33];
    int tx = threadIdx.x & 31, ty = threadIdx.x >> 5;
    size_t base = (size_t)b * DD * HWN;
    for (int rr = ty; rr < 32; rr += 8){
        int n = n0 + tx;
        T[rr][tx] = (n < HWN) ? ldin<DT>(know, base + (size_t)(g0 + rr) * HWN + n) : 0.f;
    }
    __syncthreads();
    for (int rr = ty; rr < 32; rr += 8){
        int n = n0 + rr;
        if (n < HWN) knowT[((size_t)bl * HWN + n) * DD + g0 + tx] = f2b(T[tx][rr]);
    }
}

// ---------------- MFMA GEMM 1: pkT[M,512] = knowT[M,512] @ WkT^T + bk ----------------
// 128x128 tile, flat grid, r-fastest decode when swz (same-r c-tiles -> same XCD).
__global__ __launch_bounds__(256) void g1_mfma(const bf16* __restrict__ A,
                                               const bf16* __restrict__ BT,
                                               const float* __restrict__ bkf,
                                               bf16* __restrict__ C, int nR, int swz){
    __shared__ __align__(16) bf16 As[128 * AP];
    __shared__ __align__(16) bf16 Bs[128 * AP];
    const int tid = threadIdx.x, lane = tid & 63, wave = tid >> 6;
    const int q = lane >> 4, mr = lane & 15;
    int idb = blockIdx.x, rt, ct;
    if (swz){ rt = idb % nR; ct = idb / nR; } else { ct = idb & 3; rt = idb >> 2; }
    const int r0 = rt * 128, c0 = ct * 128;
    f4v acc[2][8];
    #pragma unroll
    for (int t = 0; t < 2; ++t)
        #pragma unroll
        for (int j = 0; j < 8; ++j){ f4v z = {0.f,0.f,0.f,0.f}; acc[t][j] = z; }
    for (int k0 = 0; k0 < DD; k0 += 32){
        #pragma unroll
        for (int cc = 0; cc < 2; ++cc){
            int c = tid + cc * 256;
            int row = c >> 2, ko = (c & 3) * 8;
            *(float4*)&As[row * AP + ko] =
                *(const float4*)(A + (size_t)(r0 + row) * DD + k0 + ko);
        }
        #pragma unroll
        for (int cc = 0; cc < 2; ++cc){
            int c = tid + cc * 256;
            int col = c >> 2, ko = (c & 3) * 8;
            *(float4*)&Bs[col * AP + ko] =
                *(const float4*)(BT + (size_t)(c0 + col) * DD + k0 + ko);
        }
        __syncthreads();
        s8v a0 = *(const s8v*)&As[(wave * 32 + mr) * AP + q * 8];
        s8v a1 = *(const s8v*)&As[(wave * 32 + 16 + mr) * AP + q * 8];
        #pragma unroll
        for (int j = 0; j < 8; ++j){
            s8v b = *(const s8v*)&Bs[(j * 16 + mr) * AP + q * 8];
            acc[0][j] = __builtin_amdgcn_mfma_f32_16x16x32_bf16(a0, b, acc[0][j], 0, 0, 0);
            acc[1][j] = __builtin_amdgcn_mfma_f32_16x16x32_bf16(a1, b, acc[1][j], 0, 0, 0);
        }
        __syncthreads();
    }
    #pragma unroll
    for (int t = 0; t < 2; ++t)
        #pragma unroll
        for (int j = 0; j < 8; ++j)
            #pragma unroll
            for (int i = 0; i < 4; ++i){
                int row = r0 + wave * 32 + t * 16 + q * 4 + i;
                int col = c0 + j * 16 + mr;
                C[(size_t)row * DD + col] = f2b(acc[t][j][i] + bkf[col]);
            }
}

// ---------------- MFMA GEMM 2: h = [pk*pm , pk] @ Wc1[0:1024]; relu; dot u ----------
// K in [0,1024): A re-staged with pm scaling for k<512 (round-4 proven dataflow).
// Output: deterministic per-ct partials lpart[ct][globalrow] (no atomics).
__global__ __launch_bounds__(256) void g2_mfma(const bf16* __restrict__ Apk,
                                               const bf16* __restrict__ BT,
                                               const float* __restrict__ pmf,
                                               const float* __restrict__ t3b,
                                               const float* __restrict__ uf,
                                               float* __restrict__ lpart,
                                               int b0, int nR, int swz){
    __shared__ __align__(16) bf16 As[128 * AP];
    __shared__ __align__(16) bf16 Bs[128 * AP];
    const int tid = threadIdx.x, lane = tid & 63, wave = tid >> 6;
    const int q = lane >> 4, mr = lane & 15;
    int idb = blockIdx.x, rt, ct;
    if (swz){ rt = idb % nR; ct = idb / nR; } else { ct = idb & 3; rt = idb >> 2; }
    const int r0 = rt * 128, c0 = ct * 128;
    f4v acc[2][8];
    #pragma unroll
    for (int t = 0; t < 2; ++t)
        #pragma unroll
        for (int j = 0; j < 8; ++j){ f4v z = {0.f,0.f,0.f,0.f}; acc[t][j] = z; }
    for (int k0 = 0; k0 < 2 * DD; k0 += 32){
        #pragma unroll
        for (int cc = 0; cc < 2; ++cc){
            int c = tid + cc * 256;
            int row = c >> 2, ko = (c & 3) * 8;
            int ksrc = (k0 + ko) & (DD - 1);
            float4 v = *(const float4*)(Apk + (size_t)(r0 + row) * DD + ksrc);
            alignas(16) bf16 h[8];
            *(float4*)h = v;
            if (k0 < DD){
                int b = b0 + (r0 + row) / HWN;
                const float* pp = pmf + (size_t)b * DD + ksrc;
                #pragma unroll
                for (int i2 = 0; i2 < 8; ++i2) h[i2] = f2b(b2f(h[i2]) * pp[i2]);
            }
            *(float4*)&As[row * AP + ko] = *(const float4*)h;
        }
        #pragma unroll
        for (int cc = 0; cc < 2; ++cc){
            int c = tid + cc * 256;
            int col = c >> 2, ko = (c & 3) * 8;
            *(float4*)&Bs[col * AP + ko] =
                *(const float4*)(BT + (size_t)(c0 + col) * (2 * DD) + k0 + ko);
        }
        __syncthreads();
        s8v a0 = *(const s8v*)&As[(wave * 32 + mr) * AP + q * 8];
        s8v a1 = *(const s8v*)&As[(wave * 32 + 16 + mr) * AP + q * 8];
        #pragma unroll
        for (int j = 0; j < 8; ++j){
            s8v b = *(const s8v*)&Bs[(j * 16 + mr) * AP + q * 8];
            acc[0][j] = __builtin_amdgcn_mfma_f32_16x16x32_bf16(a0, b, acc[0][j], 0, 0, 0);
            acc[1][j] = __builtin_amdgcn_mfma_f32_16x16x32_bf16(a1, b, acc[1][j], 0, 0, 0);
        }
        __syncthreads();
    }
    float part[2][4] = {};
    #pragma unroll
    for (int t = 0; t < 2; ++t)
        #pragma unroll
        for (int j = 0; j < 8; ++j)
            #pragma unroll
            for (int i = 0; i < 4; ++i){
                int row = r0 + wave * 32 + t * 16 + q * 4 + i;
                int b = b0 + row / HWN;
                int col = c0 + j * 16 + mr;
                float hv = acc[t][j][i] + t3b[(size_t)b * DD + col];
                part[t][i] += fmaxf(hv, 0.f) * uf[(size_t)b * DD + col];
            }
    #pragma unroll
    for (int t = 0; t < 2; ++t)
        #pragma unroll
        for (int i = 0; i < 4; ++i){
            float v = part[t][i];
            v += __shfl_xor(v, 1, 16);
            v += __shfl_xor(v, 2, 16);
            v += __shfl_xor(v, 4, 16);
            v += __shfl_xor(v, 8, 16);
            if (mr == 0){
                int row = r0 + wave * 32 + t * 16 + q * 4 + i;
                lpart[(size_t)ct * (BB * HWN) + (size_t)b0 * HWN + row] = v;
            }
        }
}

// ---------------- deterministic logit reduce: logit = bias_r + sum_ct lpart ----------------
__global__ void reduce_logit_k(const float* __restrict__ lpart, const float* __restrict__ bias_r,
                               float* __restrict__ logit){
    int i = blockIdx.x * 256 + threadIdx.x;
    const int T = BB * HWN;
    if (i < T)
        logit[i] = bias_r[i / HWN] + lpart[i] + lpart[T + i] + lpart[2*T + i] + lpart[3*T + i];
}

// ---------------- fast small GEMM: LDS-free, one 16x16 MFMA tile per wave ----------------
struct SSeg { const void* A; int a_ws, lda, K, koff; };
struct SP {
    SSeg s[2]; int nseg;
    const bf16* BT; int ldb;       // BT[n][k] bf16
    const float* amul;             // optional per-k multiplier on A (seg 0 only)
    const void* bias;              // raw input dtype, may be null
    float* C; int M, N, act;       // act: 0 none, 1 tanh
};

template<int DT>
__global__ __launch_bounds__(256) void sgemm_k(SP p, const int* __restrict__ flag){
    if (*flag != DT) return;
    const int tid = threadIdx.x, lane = tid & 63, w = tid >> 6;
    const int q = lane >> 4, mr = lane & 15;
    const int n0 = blockIdx.x * 16, m0 = blockIdx.y * 64 + w * 16;
    f4v acc = {0.f,0.f,0.f,0.f};
    for (int sg = 0; sg < p.nseg; ++sg){
        const SSeg s = p.s[sg];
        const float* amul = (sg == 0) ? p.amul : nullptr;
        #pragma unroll 4
        for (int k0 = 0; k0 < s.K; k0 += 32){
            const int kk = k0 + q * 8;
            union { bf16 h[8]; s8v v; } a;
            if (s.a_ws || DT == 0){
                const float* Af = (const float*)s.A + (size_t)(m0 + mr) * s.lda + kk;
                float4 f0 = *(const float4*)Af;
                float4 f1 = *(const float4*)(Af + 4);
                float f[8] = {f0.x, f0.y, f0.z, f0.w, f1.x, f1.y, f1.z, f1.w};
                if (amul){
                    #pragma unroll
                    for (int j = 0; j < 8; ++j) f[j] *= amul[kk + j];
                }
                #pragma unroll
                for (int j = 0; j < 8; ++j) a.h[j] = f2b(f[j]);
            } else {
                a.v = *(const s8v*)((const bf16*)s.A + (size_t)(m0 + mr) * s.lda + kk);
                if (amul){
                    #pragma unroll
                    for (int j = 0; j < 8; ++j) a.h[j] = f2b(b2f(a.h[j]) * amul[kk + j]);
                }
            }
            s8v b = *(const s8v*)(p.BT + (size_t)(n0 + mr) * p.ldb + s.koff + kk);
            acc = __builtin_amdgcn_mfma_f32_16x16x32_bf16(a.v, b, acc, 0, 0, 0);
        }
    }
    #pragma unroll
    for (int i = 0; i < 4; ++i){
        int row = m0 + q * 4 + i, col = n0 + mr;
        float v = acc[i] + (p.bias ? ldin<DT>(p.bias, col) : 0.f);
        if (p.act == 1) v = tanhf(v);
        p.C[(size_t)row * p.N + col] = v;
    }
}

// ---------------- control attention ----------------
template<int DT>
__global__ __launch_bounds__(256) void attn_control_k(const float* __restrict__ cq,
                                                      const void* __restrict__ wac,
                                                      const void* __restrict__ bac,
                                                      const void* __restrict__ words,
                                                      float* __restrict__ control,
                                                      const int* __restrict__ flag){
    if (*flag != DT) return;
    const int b = blockIdx.x, tid = threadIdx.x;
    __shared__ float cw[DD];
    __shared__ float lg[SS];
    __shared__ float es[SS];
    for (int d = tid; d < DD; d += 256) cw[d] = cq[(size_t)b*DD + d] * ldin<DT>(wac, d);
    __syncthreads();
    int s = tid >> 3, l8 = tid & 7;
    float p = 0.f;
    for (int d = l8; d < DD; d += 8) p += cw[d] * ldin<DT>(words, ((size_t)b*SS + s)*DD + d);
    for (int off = 4; off; off >>= 1) p += __shfl_down(p, off, 8);
    if (l8 == 0) lg[s] = p + ldin<DT>(bac, 0);
    __syncthreads();
    if (tid == 0){
        float mx = -INFINITY;
        for (int i = 0; i < SS; ++i) mx = fmaxf(mx, lg[i]);
        float sm = 0.f;
        for (int i = 0; i < SS; ++i){ es[i] = expf(lg[i] - mx); sm += es[i]; }
        float inv = 1.f / sm;
        for (int i = 0; i < SS; ++i) es[i] *= inv;
    }
    __syncthreads();
    for (int d = tid; d < DD; d += 256){
        float c = 0.f;
        #pragma unroll 8
        for (int s2 = 0; s2 < SS; ++s2) c += es[s2] * ldin<DT>(words, ((size_t)b*SS + s2)*DD + d);
        control[(size_t)b*DD + d] = c;
    }
}

// ---------------- bias_r = dot(bc2, control*war) + bar ----------------
template<int DT>
__global__ __launch_bounds__(256) void vbias_k(const float* __restrict__ control,
                                               const void* __restrict__ war,
                                               const void* __restrict__ bc2,
                                               const void* __restrict__ bar,
                                               float* __restrict__ bias_r,
                                               const int* __restrict__ flag){
    if (*flag != DT) return;
    const int b = blockIdx.x, tid = threadIdx.x;
    __shared__ float red[256];
    float p = 0.f;
    for (int d = tid; d < DD; d += 256)
        p += ldin<DT>(bc2, d) * control[(size_t)b*DD + d] * ldin<DT>(war, d);
    red[tid] = p; __syncthreads();
    for (int off = 128; off; off >>= 1){ if (tid < off) red[tid] += red[tid + off]; __syncthreads(); }
    if (tid == 0) bias_r[b] = red[0] + ldin<DT>(bar, 0);
}

// ---------------- softmax over HW + read ----------------
template<int DT>
__global__ __launch_bounds__(256) void softmax_read_k(const float* __restrict__ logit,
                                                      const void* __restrict__ know,
                                                      float* __restrict__ readout,
                                                      const int* __restrict__ flag){
    if (*flag != DT) return;
    const int b = blockIdx.x, tid = threadIdx.x;
    __shared__ float a[HWN];
    __shared__ float red[256];
    float x = (tid < HWN) ? logit[(size_t)b*HWN + tid] : -INFINITY;
    red[tid] = x; __syncthreads();
    for (int off = 128; off; off >>= 1){ if (tid < off) red[tid] = fmaxf(red[tid], red[tid + off]); __syncthreads(); }
    float mx = red[0]; __syncthreads();
    float e = (tid < HWN) ? expf(x - mx) : 0.f;
    red[tid] = e; __syncthreads();
    for (int off = 128; off; off >>= 1){ if (tid < off) red[tid] += red[tid + off]; __syncthreads(); }
    float inv = 1.f / red[0];
    if (tid < HWN) a[tid] = e * inv;
    __syncthreads();
    for (int d = tid; d < DD; d += 256){
        size_t base = ((size_t)b*DD + d) * HWN;
        float sum = 0.f;
        if (DT){
            const ushort4* k4 = (const ushort4*)((const unsigned short*)know + base);
            #pragma unroll 7
            for (int c = 0; c < HWN/4; ++c){
                ushort4 u4 = k4[c];
                sum += a[4*c+0]*us2f(u4.x) + a[4*c+1]*us2f(u4.y)
                     + a[4*c+2]*us2f(u4.z) + a[4*c+3]*us2f(u4.w);
            }
        } else {
            const float4* k4 = (const float4*)((const float*)know + base);
            #pragma unroll 7
            for (int c = 0; c < HWN/4; ++c){
                float4 f4 = k4[c];
                sum += a[4*c+0]*f4.x + a[4*c+1]*f4.y + a[4*c+2]*f4.z + a[4*c+3]*f4.w;
            }
        }
        readout[(size_t)b*DD + d] = sum;
    }
}

// ---------------- final write ----------------
template<int DT>
__global__ void writeout_k(const float* __restrict__ control, const float* __restrict__ nm,
                           void* __restrict__ out, const int* __restrict__ flag){
    if (*flag != DT) return;
    int i = blockIdx.x * 256 + threadIdx.x;
    const int NBD = BB * DD;
    float v;
    if (i < NBD) v = control[i];
    else if (i < 2*NBD) v = nm[i - NBD];
    else return;
    if (DT) ((bf16*)out)[i] = f2b(v);
    else    ((float*)out)[i] = v;
}

extern "C" void kernel_launch(void* const* d_in, const int* in_sizes, int n_in,
                              void* d_out, int out_size, void* d_ws, size_t ws_size,
                              hipStream_t stream){
    const void* words    = d_in[0];
    const void* question = d_in[1];
    const void* know     = d_in[2];
    const void* control0 = d_in[3];
    const void* memory0  = d_in[4];
    const void* Wsc = d_in[5];   const void* bsc = d_in[6];
    const void* Wp  = d_in[7];   const void* bp  = d_in[8];
    const void* Wcq = d_in[9];   const void* bcq = d_in[10];
    const void* wac = d_in[11];  const void* bac = d_in[12];
    const void* Wm  = d_in[13];  const void* bm  = d_in[14];
    const void* Wk  = d_in[15];  const void* bk  = d_in[16];
    const void* Wc1 = d_in[17];  const void* bc1 = d_in[18];
    const void* Wc2 = d_in[19];  const void* bc2 = d_in[20];
    const void* war = d_in[21];  const void* bar = d_in[22];
    // d_in[23..26] dead: softmax over singleton axis == 1 => attn_mem == memory0
    const void* Wwcat = d_in[27]; const void* bwcat = d_in[28];

    int* flag = (int*)d_ws;
    float* F = ((float*)d_ws) + 16;
    const int NBD = BB * DD;
    float* q_   = F;
    float* pa   = F + 1*NBD;
    float* cq   = F + 2*NBD;
    float* ctrl = F + 3*NBD;
    float* pm   = F + 4*NBD;
    float* t3b  = F + 5*NBD;
    float* u_   = F + 6*NBD;
    float* rd   = F + 7*NBD;
    float* nm   = F + 8*NBD;
    float* bias_r = F + 9*NBD;                  // [B]
    float* logit  = bias_r + BB;                // [B*HW]
    float* warf   = logit + BB*HWN;             // [D]
    float* bkf    = warf + DD;                  // [D]
    float* lpart  = bkf + DD;                   // [4][B*HW]
    size_t off_f = 16 + 9*(size_t)NBD + BB + (size_t)BB*HWN + 2*DD + 4*(size_t)BB*HWN;
    size_t byte_off = (off_f * 4 + 255) & ~(size_t)255;
    bf16* WB = (bf16*)((char*)d_ws + byte_off);
    bf16* WscT   = WB;                          // [512][1024]
    bf16* WcqT   = WscT  + (size_t)DD*2*DD;     // [512][1024]
    bf16* Wc1T2  = WcqT  + (size_t)DD*2*DD;     // [512][1024]
    bf16* WwcatF = Wc1T2 + (size_t)DD*2*DD;     // [512][1024]
    bf16* WpT    = WwcatF+ (size_t)DD*2*DD;     // [512][512]
    bf16* WmT    = WpT   + (size_t)DD*DD;
    bf16* Wc1t3T = WmT   + (size_t)DD*DD;
    bf16* WkT    = Wc1t3T+ (size_t)DD*DD;
    bf16* Wc2cv  = WkT   + (size_t)DD*DD;
    size_t big_off = (byte_off + ((size_t)DD*2*DD*4 + (size_t)DD*DD*5) * sizeof(bf16) + 255) & ~(size_t)255;

    size_t per_batch = (size_t)HWN * DD * sizeof(bf16) * 2;     // knowT + pkT
    size_t avail = (ws_size > big_off) ? (ws_size - big_off) : 0;
    int CB = (int)(avail / per_batch);
    CB &= ~31;                                                  // multiple of 32 (M % 128 == 0)
    if (CB > BB) CB = BB;
    if (CB < 32) CB = 32;
    bf16* knowT = (bf16*)((char*)d_ws + big_off);               // [CB][196][512]
    bf16* pkT   = knowT + (size_t)CB * HWN * DD;                // [CB][196][512]

    dim3 blk(256);

    detect_k<<<dim3(1), blk, 0, stream>>>(question, flag);

    // ---- fused weight prep ----
    {
        PrepP P0; int bo = 0;
        auto J = [&](const void* s, const void* s2, bf16* d, int R, int C, int ldd,
                     int kofs, int mode, int idx){
            int nb = (mode == 3) ? 1 : ((R >> 5) * (C >> 5));
            P0.j[idx] = PJob{ s, s2, d, R, C, ldd, kofs, mode, nb, bo };
            bo += nb;
        };
        J(Wsc,   nullptr, WscT,   2*DD, DD, 2*DD, 0,   0, 0);
        J(Wp,    nullptr, WpT,    DD,   DD, DD,   0,   0, 1);
        J(Wcq,   nullptr, WcqT,   2*DD, DD, 2*DD, 0,   0, 2);
        J(Wm,    nullptr, WmT,    DD,   DD, DD,   0,   0, 3);
        J(Wc1,   nullptr, Wc1T2,  2*DD, DD, 2*DD, 0,   0, 4);
        J(nullptr,nullptr,Wc1t3T, DD,   DD, DD,   0,   0, 5);   // src set per-dtype below
        J(Wk,    nullptr, WkT,    DD,   DD, DD,   0,   0, 6);
        J(Wwcat, nullptr, WwcatF, DD,   DD, 2*DD, 0,   0, 7);
        J(nullptr,nullptr,WwcatF, DD,   DD, 2*DD, 512, 1, 8);   // src,src2 per-dtype
        J(Wc2,   nullptr, Wc2cv,  DD,   DD, DD,   0,   2, 9);
        J(nullptr,nullptr,nullptr,0,    0,  0,    0,   3, 10);
        P0.war = war; P0.bk = bk; P0.warf = warf; P0.bkf = bkf;
        PrepP P1 = P0;
        P0.j[5].s = (const void*)((const float*)Wc1 + (size_t)2*DD*DD);
        P1.j[5].s = (const void*)((const bf16*) Wc1 + (size_t)2*DD*DD);
        P0.j[8].s = (const void*)((const float*)Wwcat + (size_t)DD*DD);
        P1.j[8].s = (const void*)((const bf16*) Wwcat + (size_t)DD*DD);
        P0.j[8].s2 = (const void*)((const float*)Wwcat + (size_t)2*DD*DD);
        P1.j[8].s2 = (const void*)((const bf16*) Wwcat + (size_t)2*DD*DD);
        dim3 gp(bo);
        prep_k<0><<<gp, blk, 0, stream>>>(P0, flag);
        prep_k<1><<<gp, blk, 0, stream>>>(P1, flag);
    }

    dim3 g_s(DD/16, BB/64);     // (32, 4)
    SP p;
    #define LAUNCH_S(P) do { \
        sgemm_k<0><<<g_s, blk, 0, stream>>>(P, flag); \
        sgemm_k<1><<<g_s, blk, 0, stream>>>(P, flag); } while(0)

    // q = tanh(question @ Wsc + bsc)
    p = SP{}; p.nseg = 1;
    p.s[0] = SSeg{ question, 0, 2*DD, 2*DD, 0 };
    p.BT = WscT; p.ldb = 2*DD; p.amul = nullptr;
    p.bias = bsc; p.C = q_; p.M = BB; p.N = DD; p.act = 1;
    LAUNCH_S(p);
    // pa = q @ Wp + bp
    p = SP{}; p.nseg = 1;
    p.s[0] = SSeg{ q_, 1, DD, DD, 0 };
    p.BT = WpT; p.ldb = DD; p.amul = nullptr;
    p.bias = bp; p.C = pa; p.M = BB; p.N = DD; p.act = 0;
    LAUNCH_S(p);
    // cq = [control0, pa] @ Wcq + bcq
    p = SP{}; p.nseg = 2;
    p.s[0] = SSeg{ control0, 0, DD, DD, 0 };
    p.s[1] = SSeg{ pa,       1, DD, DD, 512 };
    p.BT = WcqT; p.ldb = 2*DD; p.amul = nullptr;
    p.bias = bcq; p.C = cq; p.M = BB; p.N = DD; p.act = 0;
    LAUNCH_S(p);
    // control
    attn_control_k<0><<<dim3(BB), blk, 0, stream>>>(cq, wac, bac, words, ctrl, flag);
    attn_control_k<1><<<dim3(BB), blk, 0, stream>>>(cq, wac, bac, words, ctrl, flag);
    // pm = memory0 @ Wm + bm
    p = SP{}; p.nseg = 1;
    p.s[0] = SSeg{ memory0, 0, DD, DD, 0 };
    p.BT = WmT; p.ldb = DD; p.amul = nullptr;
    p.bias = bm; p.C = pm; p.M = BB; p.N = DD; p.act = 0;
    LAUNCH_S(p);
    // t3b = pm @ Wc1[2D:3D] + bc1
    p = SP{}; p.nseg = 1;
    p.s[0] = SSeg{ pm, 1, DD, DD, 0 };
    p.BT = Wc1t3T; p.ldb = DD; p.amul = nullptr;
    p.bias = bc1; p.C = t3b; p.M = BB; p.N = DD; p.act = 0;
    LAUNCH_S(p);
    // bias_r
    vbias_k<0><<<dim3(BB), blk, 0, stream>>>(ctrl, war, bc2, bar, bias_r, flag);
    vbias_k<1><<<dim3(BB), blk, 0, stream>>>(ctrl, war, bc2, bar, bias_r, flag);
    // u[b,e] = sum_d Wc2[e,d] * (ctrl[b,d]*war[d])
    p = SP{}; p.nseg = 1;
    p.s[0] = SSeg{ ctrl, 1, DD, DD, 0 };
    p.BT = Wc2cv; p.ldb = DD; p.amul = warf;
    p.bias = nullptr; p.C = u_; p.M = BB; p.N = DD; p.act = 0;
    LAUNCH_S(p);

    // chunked MFMA pipeline: transpose know -> G1 -> G2
    for (int b0 = 0; b0 < BB; b0 += CB){
        int cb = (b0 + CB <= BB) ? CB : (BB - b0);
        int M = cb * HWN;                           // multiple of 128
        dim3 g_tr((HWN + 31)/32, DD/32, cb);
        tr_know<0><<<g_tr, blk, 0, stream>>>(know, knowT, b0, flag);
        tr_know<1><<<g_tr, blk, 0, stream>>>(know, knowT, b0, flag);
        int nR = M / 128;
        int swz = (nR % 8 == 0) ? 1 : 0;            // same-r c-tiles -> same XCD
        dim3 gflat(4 * nR);
        g1_mfma<<<gflat, blk, 0, stream>>>(knowT, WkT, bkf, pkT, nR, swz);
        g2_mfma<<<gflat, blk, 0, stream>>>(pkT, Wc1T2, pm, t3b, u_, lpart, b0, nR, swz);
    }

    // deterministic logit assembly, then softmax + read
    reduce_logit_k<<<dim3((BB*HWN + 255)/256), blk, 0, stream>>>(lpart, bias_r, logit);
    softmax_read_k<0><<<dim3(BB), blk, 0, stream>>>(logit, know, rd, flag);
    softmax_read_k<1><<<dim3(BB), blk, 0, stream>>>(logit, know, rd, flag);
    // next_mem = [rd, memory0] @ WwcatF^T + bwcat
    p = SP{}; p.nseg = 2;
    p.s[0] = SSeg{ rd,      1, DD, DD, 0 };
    p.s[1] = SSeg{ memory0, 0, DD, DD, 512 };
    p.BT = WwcatF; p.ldb = 2*DD; p.amul = nullptr;
    p.bias = bwcat; p.C = nm; p.M = BB; p.N = DD; p.act = 0;
    LAUNCH_S(p);
    // out = [control ; next_mem]
    writeout_k<0><<<dim3(2*NBD/256), blk, 0, stream>>>(ctrl, nm, d_out, flag);
    writeout_k<1><<<dim3(2*NBD/256), blk, 0, stream>>>(ctrl, nm, d_out, flag);
    #undef LAUNCH_S
}

// Round 7
// 633.595 us; speedup vs baseline: 1.1343x; 1.1343x over previous
//
#include <hip/hip_runtime.h>
#include <hip/hip_bf16.h>
#include <math.h>

typedef __hip_bfloat16 bf16;
typedef __attribute__((ext_vector_type(8))) short s8v;   // 8 bf16 = 4 VGPR (MFMA A/B frag)
typedef __attribute__((ext_vector_type(4))) float f4v;   // MFMA C/D frag

// B=256, S=32, D=512, HW=196
#define BB 256
#define SS 32
#define DD 512
#define HWN 196
#define AP 40   // LDS row pitch (bf16): 80 B -> conflict-free b128 frag reads

__device__ __forceinline__ float b2f(bf16 x){ return __bfloat162float(x); }
__device__ __forceinline__ bf16 f2b(float x){ return __float2bfloat16(x); }
__device__ __forceinline__ float us2f(unsigned short u){
    union { unsigned int i; float f; } t; t.i = ((unsigned int)u) << 16; return t.f;
}
// dt: 1 = inputs are bf16, 0 = inputs are fp32 (runtime-uniform)
__device__ __forceinline__ float ldin(int dt, const void* p, size_t i){
    return dt ? b2f(((const bf16*)p)[i]) : ((const float*)p)[i];
}

// ---------------- dtype detector ----------------
__global__ void detect_k(const void* q, int* flag){
    __shared__ int cnt;
    if (threadIdx.x == 0) cnt = 0;
    __syncthreads();
    const unsigned short* u = (const unsigned short*)q;
    unsigned short v = u[threadIdx.x * 4];
    int e = (v >> 7) & 0xFF;
    atomicAdd(&cnt, (e >= 100 && e <= 140) ? 1 : 0);
    __syncthreads();
    if (threadIdx.x == 0) *flag = (cnt > 128) ? 1 : 0;
}

// ---------------- fused weight prep (runtime dt; per-dtype alt pointers) ----------------
struct PJob { const void* s; const void* s_b; const void* s2; const void* s2_b;
              bf16* d; int R, C, ldd, kofs, mode, boff; };
struct PrepP { PJob j[11]; const void* war; const void* bk; float* warf; float* bkf; };

__global__ __launch_bounds__(256) void prep_k(PrepP P, const int* __restrict__ flag){
    const int dt = *flag;
    __shared__ float T[32][33];
    int bx = blockIdx.x;
    int ji = 0;
    #pragma unroll
    for (int i = 0; i < 11; ++i) if (bx >= P.j[i].boff) ji = i;
    PJob jb = P.j[ji];
    const void* src  = dt ? jb.s_b  : jb.s;
    const void* src2 = dt ? jb.s2_b : jb.s2;
    int t = bx - jb.boff;
    int tx = threadIdx.x & 31, ty = threadIdx.x >> 5;
    if (jb.mode == 3){
        for (int i = threadIdx.x; i < DD; i += 256){
            P.warf[i] = ldin(dt, P.war, i);
            P.bkf[i]  = ldin(dt, P.bk, i);
        }
        return;
    }
    int nrt = jb.R >> 5;
    int r0 = (t % nrt) << 5, c0 = (t / nrt) << 5;
    if (jb.mode == 2){
        for (int rr = ty; rr < 32; rr += 8)
            jb.d[(size_t)(r0 + rr) * jb.ldd + jb.kofs + c0 + tx] =
                f2b(ldin(dt, src, (size_t)(r0 + rr) * jb.C + c0 + tx));
        return;
    }
    for (int rr = ty; rr < 32; rr += 8){
        float v = ldin(dt, src, (size_t)(r0 + rr) * jb.C + c0 + tx);
        if (jb.mode == 1) v += ldin(dt, src2, (size_t)(r0 + rr) * jb.C + c0 + tx);
        T[rr][tx] = v;
    }
    __syncthreads();
    for (int rr = ty; rr < 32; rr += 8)
        jb.d[(size_t)(c0 + rr) * jb.ldd + jb.kofs + r0 + tx] = f2b(T[tx][rr]);
}

// ---------------- know transpose (per chunk) ----------------
__global__ void tr_know(const void* __restrict__ know, bf16* __restrict__ knowT, int b0,
                        const int* __restrict__ flag){
    const int dt = *flag;
    int bl = blockIdx.z, b = b0 + bl;
    int n0 = blockIdx.x * 32, g0 = blockIdx.y * 32;
    __shared__ float T[32][33];
    int tx = threadIdx.x & 31, ty = threadIdx.x >> 5;
    size_t base = (size_t)b * DD * HWN;
    for (int rr = ty; rr < 32; rr += 8){
        int n = n0 + tx;
        T[rr][tx] = (n < HWN) ? ldin(dt, know, base + (size_t)(g0 + rr) * HWN + n) : 0.f;
    }
    __syncthreads();
    for (int rr = ty; rr < 32; rr += 8){
        int n = n0 + rr;
        if (n < HWN) knowT[((size_t)bl * HWN + n) * DD + g0 + tx] = f2b(T[tx][rr]);
    }
}

// ---- block swizzle: 8 c-tiles of one rt within a 64-id window, same XCD (id%8==rt%8) ----
__device__ __forceinline__ void tile_decode(int idb, int swz, int& rt, int& ct){
    if (swz){ int g = idb >> 6, w = idb & 63; rt = g * 8 + (w & 7); ct = w >> 3; }
    else    { ct = idb & 7; rt = idb >> 3; }
}

// ---------------- MFMA GEMM 1: pkT[M,512] = knowT[M,512] @ WkT^T + bk  (128x64 tile) ----
__global__ __launch_bounds__(256) void g1_mfma(const bf16* __restrict__ A,
                                               const bf16* __restrict__ BT,
                                               const float* __restrict__ bkf,
                                               bf16* __restrict__ C, int swz){
    __shared__ __align__(16) bf16 As[128 * AP];
    __shared__ __align__(16) bf16 Bs[64 * AP];
    const int tid = threadIdx.x, lane = tid & 63, wave = tid >> 6;
    const int q = lane >> 4, mr = lane & 15;
    int rt, ct; tile_decode(blockIdx.x, swz, rt, ct);
    const int r0 = rt * 128, c0 = ct * 64;
    f4v acc[2][4];
    #pragma unroll
    for (int t = 0; t < 2; ++t)
        #pragma unroll
        for (int j = 0; j < 4; ++j){ f4v z = {0.f,0.f,0.f,0.f}; acc[t][j] = z; }
    for (int k0 = 0; k0 < DD; k0 += 32){
        #pragma unroll
        for (int cc = 0; cc < 2; ++cc){
            int c = tid + cc * 256;
            int row = c >> 2, ko = (c & 3) * 8;
            *(float4*)&As[row * AP + ko] =
                *(const float4*)(A + (size_t)(r0 + row) * DD + k0 + ko);
        }
        {
            int col = tid >> 2, ko = (tid & 3) * 8;
            *(float4*)&Bs[col * AP + ko] =
                *(const float4*)(BT + (size_t)(c0 + col) * DD + k0 + ko);
        }
        __syncthreads();
        s8v a0 = *(const s8v*)&As[(wave * 32 + mr) * AP + q * 8];
        s8v a1 = *(const s8v*)&As[(wave * 32 + 16 + mr) * AP + q * 8];
        #pragma unroll
        for (int j = 0; j < 4; ++j){
            s8v b = *(const s8v*)&Bs[(j * 16 + mr) * AP + q * 8];
            acc[0][j] = __builtin_amdgcn_mfma_f32_16x16x32_bf16(a0, b, acc[0][j], 0, 0, 0);
            acc[1][j] = __builtin_amdgcn_mfma_f32_16x16x32_bf16(a1, b, acc[1][j], 0, 0, 0);
        }
        __syncthreads();
    }
    #pragma unroll
    for (int t = 0; t < 2; ++t)
        #pragma unroll
        for (int j = 0; j < 4; ++j)
            #pragma unroll
            for (int i = 0; i < 4; ++i){
                int row = r0 + wave * 32 + t * 16 + q * 4 + i;
                int col = c0 + j * 16 + mr;
                C[(size_t)row * DD + col] = f2b(acc[t][j][i] + bkf[col]);
            }
}

// ---------------- MFMA GEMM 2: h = [pk*pm , pk] @ Wc1[0:1024]; relu; dot u ----------
// 128x64 tile, K in [0,1024), A re-staged with pm scaling for k<512 (proven dataflow).
// Deterministic per-ct partials lpart[ct][globalrow] (ct in [0,8), no atomics).
__global__ __launch_bounds__(256) void g2_mfma(const bf16* __restrict__ Apk,
                                               const bf16* __restrict__ BT,
                                               const float* __restrict__ pmf,
                                               const float* __restrict__ t3b,
                                               const float* __restrict__ uf,
                                               float* __restrict__ lpart,
                                               int b0, int swz){
    __shared__ __align__(16) bf16 As[128 * AP];
    __shared__ __align__(16) bf16 Bs[64 * AP];
    const int tid = threadIdx.x, lane = tid & 63, wave = tid >> 6;
    const int q = lane >> 4, mr = lane & 15;
    int rt, ct; tile_decode(blockIdx.x, swz, rt, ct);
    const int r0 = rt * 128, c0 = ct * 64;
    f4v acc[2][4];
    #pragma unroll
    for (int t = 0; t < 2; ++t)
        #pragma unroll
        for (int j = 0; j < 4; ++j){ f4v z = {0.f,0.f,0.f,0.f}; acc[t][j] = z; }
    for (int k0 = 0; k0 < 2 * DD; k0 += 32){
        #pragma unroll
        for (int cc = 0; cc < 2; ++cc){
            int c = tid + cc * 256;
            int row = c >> 2, ko = (c & 3) * 8;
            int ksrc = (k0 + ko) & (DD - 1);
            float4 v = *(const float4*)(Apk + (size_t)(r0 + row) * DD + ksrc);
            alignas(16) bf16 h[8];
            *(float4*)h = v;
            if (k0 < DD){
                int b = b0 + (r0 + row) / HWN;
                const float* pp = pmf + (size_t)b * DD + ksrc;
                #pragma unroll
                for (int i2 = 0; i2 < 8; ++i2) h[i2] = f2b(b2f(h[i2]) * pp[i2]);
            }
            *(float4*)&As[row * AP + ko] = *(const float4*)h;
        }
        {
            int col = tid >> 2, ko = (tid & 3) * 8;
            *(float4*)&Bs[col * AP + ko] =
                *(const float4*)(BT + (size_t)(c0 + col) * (2 * DD) + k0 + ko);
        }
        __syncthreads();
        s8v a0 = *(const s8v*)&As[(wave * 32 + mr) * AP + q * 8];
        s8v a1 = *(const s8v*)&As[(wave * 32 + 16 + mr) * AP + q * 8];
        #pragma unroll
        for (int j = 0; j < 4; ++j){
            s8v b = *(const s8v*)&Bs[(j * 16 + mr) * AP + q * 8];
            acc[0][j] = __builtin_amdgcn_mfma_f32_16x16x32_bf16(a0, b, acc[0][j], 0, 0, 0);
            acc[1][j] = __builtin_amdgcn_mfma_f32_16x16x32_bf16(a1, b, acc[1][j], 0, 0, 0);
        }
        __syncthreads();
    }
    float part[2][4] = {};
    #pragma unroll
    for (int t = 0; t < 2; ++t)
        #pragma unroll
        for (int j = 0; j < 4; ++j)
            #pragma unroll
            for (int i = 0; i < 4; ++i){
                int row = r0 + wave * 32 + t * 16 + q * 4 + i;
                int b = b0 + row / HWN;
                int col = c0 + j * 16 + mr;
                float hv = acc[t][j][i] + t3b[(size_t)b * DD + col];
                part[t][i] += fmaxf(hv, 0.f) * uf[(size_t)b * DD + col];
            }
    #pragma unroll
    for (int t = 0; t < 2; ++t)
        #pragma unroll
        for (int i = 0; i < 4; ++i){
            float v = part[t][i];
            v += __shfl_xor(v, 1, 16);
            v += __shfl_xor(v, 2, 16);
            v += __shfl_xor(v, 4, 16);
            v += __shfl_xor(v, 8, 16);
            if (mr == 0){
                int row = r0 + wave * 32 + t * 16 + q * 4 + i;
                lpart[(size_t)ct * (BB * HWN) + (size_t)b0 * HWN + row] = v;
            }
        }
}

// ---------------- deterministic logit reduce: logit = bias_r + sum_ct lpart ----------------
__global__ void reduce_logit_k(const float* __restrict__ lpart, const float* __restrict__ bias_r,
                               float* __restrict__ logit){
    int i = blockIdx.x * 256 + threadIdx.x;
    const int T = BB * HWN;
    if (i < T){
        float s = bias_r[i / HWN];
        #pragma unroll
        for (int c = 0; c < 8; ++c) s += lpart[(size_t)c * T + i];
        logit[i] = s;
    }
}

// ---------------- fast small GEMM: LDS-free, one 16x16 MFMA tile per wave ----------------
struct SSeg { const void* A; int a_ws, lda, K, koff; };
struct SP {
    SSeg s[2]; int nseg;
    const bf16* BT; int ldb;       // BT[n][k] bf16
    const float* amul;             // optional per-k multiplier on A (seg 0 only)
    const void* bias;              // raw input dtype, may be null
    float* C; int M, N, act;       // act: 0 none, 1 tanh
};

__global__ __launch_bounds__(256) void sgemm_k(SP p, const int* __restrict__ flag){
    const int dt = *flag;
    const int tid = threadIdx.x, lane = tid & 63, w = tid >> 6;
    const int q = lane >> 4, mr = lane & 15;
    const int n0 = blockIdx.x * 16, m0 = blockIdx.y * 64 + w * 16;
    f4v acc = {0.f,0.f,0.f,0.f};
    for (int sg = 0; sg < p.nseg; ++sg){
        const SSeg s = p.s[sg];
        const float* amul = (sg == 0) ? p.amul : nullptr;
        #pragma unroll 4
        for (int k0 = 0; k0 < s.K; k0 += 32){
            const int kk = k0 + q * 8;
            union { bf16 h[8]; s8v v; } a;
            if (s.a_ws || dt == 0){
                const float* Af = (const float*)s.A + (size_t)(m0 + mr) * s.lda + kk;
                float4 f0 = *(const float4*)Af;
                float4 f1 = *(const float4*)(Af + 4);
                float f[8] = {f0.x, f0.y, f0.z, f0.w, f1.x, f1.y, f1.z, f1.w};
                if (amul){
                    #pragma unroll
                    for (int j = 0; j < 8; ++j) f[j] *= amul[kk + j];
                }
                #pragma unroll
                for (int j = 0; j < 8; ++j) a.h[j] = f2b(f[j]);
            } else {
                a.v = *(const s8v*)((const bf16*)s.A + (size_t)(m0 + mr) * s.lda + kk);
                if (amul){
                    #pragma unroll
                    for (int j = 0; j < 8; ++j) a.h[j] = f2b(b2f(a.h[j]) * amul[kk + j]);
                }
            }
            s8v b = *(const s8v*)(p.BT + (size_t)(n0 + mr) * p.ldb + s.koff + kk);
            acc = __builtin_amdgcn_mfma_f32_16x16x32_bf16(a.v, b, acc, 0, 0, 0);
        }
    }
    #pragma unroll
    for (int i = 0; i < 4; ++i){
        int row = m0 + q * 4 + i, col = n0 + mr;
        float v = acc[i] + (p.bias ? ldin(dt, p.bias, col) : 0.f);
        if (p.act == 1) v = tanhf(v);
        p.C[(size_t)row * p.N + col] = v;
    }
}

// ---------------- control attention ----------------
__global__ __launch_bounds__(256) void attn_control_k(const float* __restrict__ cq,
                                                      const void* __restrict__ wac,
                                                      const void* __restrict__ bac,
                                                      const void* __restrict__ words,
                                                      float* __restrict__ control,
                                                      const int* __restrict__ flag){
    const int dt = *flag;
    const int b = blockIdx.x, tid = threadIdx.x;
    __shared__ float cw[DD];
    __shared__ float lg[SS];
    __shared__ float es[SS];
    for (int d = tid; d < DD; d += 256) cw[d] = cq[(size_t)b*DD + d] * ldin(dt, wac, d);
    __syncthreads();
    int s = tid >> 3, l8 = tid & 7;
    float p = 0.f;
    for (int d = l8; d < DD; d += 8) p += cw[d] * ldin(dt, words, ((size_t)b*SS + s)*DD + d);
    for (int off = 4; off; off >>= 1) p += __shfl_down(p, off, 8);
    if (l8 == 0) lg[s] = p + ldin(dt, bac, 0);
    __syncthreads();
    if (tid == 0){
        float mx = -INFINITY;
        for (int i = 0; i < SS; ++i) mx = fmaxf(mx, lg[i]);
        float sm = 0.f;
        for (int i = 0; i < SS; ++i){ es[i] = expf(lg[i] - mx); sm += es[i]; }
        float inv = 1.f / sm;
        for (int i = 0; i < SS; ++i) es[i] *= inv;
    }
    __syncthreads();
    for (int d = tid; d < DD; d += 256){
        float c = 0.f;
        #pragma unroll 8
        for (int s2 = 0; s2 < SS; ++s2) c += es[s2] * ldin(dt, words, ((size_t)b*SS + s2)*DD + d);
        control[(size_t)b*DD + d] = c;
    }
}

// ---------------- bias_r = dot(bc2, control*war) + bar ----------------
__global__ __launch_bounds__(256) void vbias_k(const float* __restrict__ control,
                                               const void* __restrict__ war,
                                               const void* __restrict__ bc2,
                                               const void* __restrict__ bar,
                                               float* __restrict__ bias_r,
                                               const int* __restrict__ flag){
    const int dt = *flag;
    const int b = blockIdx.x, tid = threadIdx.x;
    __shared__ float red[256];
    float p = 0.f;
    for (int d = tid; d < DD; d += 256)
        p += ldin(dt, bc2, d) * control[(size_t)b*DD + d] * ldin(dt, war, d);
    red[tid] = p; __syncthreads();
    for (int off = 128; off; off >>= 1){ if (tid < off) red[tid] += red[tid + off]; __syncthreads(); }
    if (tid == 0) bias_r[b] = red[0] + ldin(dt, bar, 0);
}

// ---------------- softmax over HW + read ----------------
__global__ __launch_bounds__(256) void softmax_read_k(const float* __restrict__ logit,
                                                      const void* __restrict__ know,
                                                      float* __restrict__ readout,
                                                      const int* __restrict__ flag){
    const int dt = *flag;
    const int b = blockIdx.x, tid = threadIdx.x;
    __shared__ float a[HWN];
    __shared__ float red[256];
    float x = (tid < HWN) ? logit[(size_t)b*HWN + tid] : -INFINITY;
    red[tid] = x; __syncthreads();
    for (int off = 128; off; off >>= 1){ if (tid < off) red[tid] = fmaxf(red[tid], red[tid + off]); __syncthreads(); }
    float mx = red[0]; __syncthreads();
    float e = (tid < HWN) ? expf(x - mx) : 0.f;
    red[tid] = e; __syncthreads();
    for (int off = 128; off; off >>= 1){ if (tid < off) red[tid] += red[tid + off]; __syncthreads(); }
    float inv = 1.f / red[0];
    if (tid < HWN) a[tid] = e * inv;
    __syncthreads();
    for (int d = tid; d < DD; d += 256){
        size_t base = ((size_t)b*DD + d) * HWN;
        float sum = 0.f;
        if (dt){
            const ushort4* k4 = (const ushort4*)((const unsigned short*)know + base);
            #pragma unroll 7
            for (int c = 0; c < HWN/4; ++c){
                ushort4 u4 = k4[c];
                sum += a[4*c+0]*us2f(u4.x) + a[4*c+1]*us2f(u4.y)
                     + a[4*c+2]*us2f(u4.z) + a[4*c+3]*us2f(u4.w);
            }
        } else {
            const float4* k4 = (const float4*)((const float*)know + base);
            #pragma unroll 7
            for (int c = 0; c < HWN/4; ++c){
                float4 f4 = k4[c];
                sum += a[4*c+0]*f4.x + a[4*c+1]*f4.y + a[4*c+2]*f4.z + a[4*c+3]*f4.w;
            }
        }
        readout[(size_t)b*DD + d] = sum;
    }
}

// ---------------- final write ----------------
__global__ void writeout_k(const float* __restrict__ control, const float* __restrict__ nm,
                           void* __restrict__ out, const int* __restrict__ flag){
    const int dt = *flag;
    int i = blockIdx.x * 256 + threadIdx.x;
    const int NBD = BB * DD;
    float v;
    if (i < NBD) v = control[i];
    else if (i < 2*NBD) v = nm[i - NBD];
    else return;
    if (dt) ((bf16*)out)[i] = f2b(v);
    else    ((float*)out)[i] = v;
}

extern "C" void kernel_launch(void* const* d_in, const int* in_sizes, int n_in,
                              void* d_out, int out_size, void* d_ws, size_t ws_size,
                              hipStream_t stream){
    const void* words    = d_in[0];
    const void* question = d_in[1];
    const void* know     = d_in[2];
    const void* control0 = d_in[3];
    const void* memory0  = d_in[4];
    const void* Wsc = d_in[5];   const void* bsc = d_in[6];
    const void* Wp  = d_in[7];   const void* bp  = d_in[8];
    const void* Wcq = d_in[9];   const void* bcq = d_in[10];
    const void* wac = d_in[11];  const void* bac = d_in[12];
    const void* Wm  = d_in[13];  const void* bm  = d_in[14];
    const void* Wk  = d_in[15];  const void* bk  = d_in[16];
    const void* Wc1 = d_in[17];  const void* bc1 = d_in[18];
    const void* Wc2 = d_in[19];  const void* bc2 = d_in[20];
    const void* war = d_in[21];  const void* bar = d_in[22];
    // d_in[23..26] dead: softmax over singleton axis == 1 => attn_mem == memory0
    const void* Wwcat = d_in[27]; const void* bwcat = d_in[28];

    int* flag = (int*)d_ws;
    float* F = ((float*)d_ws) + 16;
    const int NBD = BB * DD;
    float* q_   = F;
    float* pa   = F + 1*NBD;
    float* cq   = F + 2*NBD;
    float* ctrl = F + 3*NBD;
    float* pm   = F + 4*NBD;
    float* t3b  = F + 5*NBD;
    float* u_   = F + 6*NBD;
    float* rd   = F + 7*NBD;
    float* nm   = F + 8*NBD;
    float* bias_r = F + 9*NBD;                  // [B]
    float* logit  = bias_r + BB;                // [B*HW]
    float* warf   = logit + BB*HWN;             // [D]
    float* bkf    = warf + DD;                  // [D]
    float* lpart  = bkf + DD;                   // [8][B*HW]
    size_t off_f = 16 + 9*(size_t)NBD + BB + (size_t)BB*HWN + 2*DD + 8*(size_t)BB*HWN;
    size_t byte_off = (off_f * 4 + 255) & ~(size_t)255;
    bf16* WB = (bf16*)((char*)d_ws + byte_off);
    bf16* WscT   = WB;                          // [512][1024]
    bf16* WcqT   = WscT  + (size_t)DD*2*DD;     // [512][1024]
    bf16* Wc1T2  = WcqT  + (size_t)DD*2*DD;     // [512][1024]
    bf16* WwcatF = Wc1T2 + (size_t)DD*2*DD;     // [512][1024]
    bf16* WpT    = WwcatF+ (size_t)DD*2*DD;     // [512][512]
    bf16* WmT    = WpT   + (size_t)DD*DD;
    bf16* Wc1t3T = WmT   + (size_t)DD*DD;
    bf16* WkT    = Wc1t3T+ (size_t)DD*DD;
    bf16* Wc2cv  = WkT   + (size_t)DD*DD;
    size_t big_off = (byte_off + ((size_t)DD*2*DD*4 + (size_t)DD*DD*5) * sizeof(bf16) + 255) & ~(size_t)255;

    size_t per_batch = (size_t)HWN * DD * sizeof(bf16) * 2;     // knowT + pkT
    size_t avail = (ws_size > big_off) ? (ws_size - big_off) : 0;
    int CB = (int)(avail / per_batch);
    CB &= ~31;                                                  // multiple of 32 (M % 128 == 0)
    if (CB > BB) CB = BB;
    if (CB < 32) CB = 32;
    bf16* knowT = (bf16*)((char*)d_ws + big_off);               // [CB][196][512]
    bf16* pkT   = knowT + (size_t)CB * HWN * DD;                // [CB][196][512]

    dim3 blk(256);

    detect_k<<<dim3(1), blk, 0, stream>>>(question, flag);

    // ---- fused weight prep (single launch, runtime dt) ----
    {
        PrepP P; int bo = 0;
        auto J = [&](const void* s, const void* sb, const void* s2, const void* s2b,
                     bf16* d, int R, int C, int ldd, int kofs, int mode, int idx){
            int nb = (mode == 3) ? 1 : ((R >> 5) * (C >> 5));
            P.j[idx] = PJob{ s, sb, s2, s2b, d, R, C, ldd, kofs, mode, bo };
            bo += nb;
        };
        const void* Wc1t3_f = (const void*)((const float*)Wc1 + (size_t)2*DD*DD);
        const void* Wc1t3_b = (const void*)((const bf16*) Wc1 + (size_t)2*DD*DD);
        const void* Ww1_f = (const void*)((const float*)Wwcat + (size_t)DD*DD);
        const void* Ww1_b = (const void*)((const bf16*) Wwcat + (size_t)DD*DD);
        const void* Ww2_f = (const void*)((const float*)Wwcat + (size_t)2*DD*DD);
        const void* Ww2_b = (const void*)((const bf16*) Wwcat + (size_t)2*DD*DD);
        J(Wsc,   Wsc,   nullptr, nullptr, WscT,   2*DD, DD, 2*DD, 0,   0, 0);
        J(Wp,    Wp,    nullptr, nullptr, WpT,    DD,   DD, DD,   0,   0, 1);
        J(Wcq,   Wcq,   nullptr, nullptr, WcqT,   2*DD, DD, 2*DD, 0,   0, 2);
        J(Wm,    Wm,    nullptr, nullptr, WmT,    DD,   DD, DD,   0,   0, 3);
        J(Wc1,   Wc1,   nullptr, nullptr, Wc1T2,  2*DD, DD, 2*DD, 0,   0, 4);
        J(Wc1t3_f, Wc1t3_b, nullptr, nullptr, Wc1t3T, DD, DD, DD, 0,   0, 5);
        J(Wk,    Wk,    nullptr, nullptr, WkT,    DD,   DD, DD,   0,   0, 6);
        J(Wwcat, Wwcat, nullptr, nullptr, WwcatF, DD,   DD, 2*DD, 0,   0, 7);
        J(Ww1_f, Ww1_b, Ww2_f,   Ww2_b,   WwcatF, DD,   DD, 2*DD, 512, 1, 8);
        J(Wc2,   Wc2,   nullptr, nullptr, Wc2cv,  DD,   DD, DD,   0,   2, 9);
        J(nullptr,nullptr,nullptr,nullptr,nullptr,0,    0,  0,    0,   3, 10);
        P.war = war; P.bk = bk; P.warf = warf; P.bkf = bkf;
        prep_k<<<dim3(bo), blk, 0, stream>>>(P, flag);
    }

    dim3 g_s(DD/16, BB/64);     // (32, 4)
    SP p;

    // q = tanh(question @ Wsc + bsc)
    p = SP{}; p.nseg = 1;
    p.s[0] = SSeg{ question, 0, 2*DD, 2*DD, 0 };
    p.BT = WscT; p.ldb = 2*DD; p.amul = nullptr;
    p.bias = bsc; p.C = q_; p.M = BB; p.N = DD; p.act = 1;
    sgemm_k<<<g_s, blk, 0, stream>>>(p, flag);
    // pa = q @ Wp + bp
    p = SP{}; p.nseg = 1;
    p.s[0] = SSeg{ q_, 1, DD, DD, 0 };
    p.BT = WpT; p.ldb = DD; p.amul = nullptr;
    p.bias = bp; p.C = pa; p.M = BB; p.N = DD; p.act = 0;
    sgemm_k<<<g_s, blk, 0, stream>>>(p, flag);
    // cq = [control0, pa] @ Wcq + bcq
    p = SP{}; p.nseg = 2;
    p.s[0] = SSeg{ control0, 0, DD, DD, 0 };
    p.s[1] = SSeg{ pa,       1, DD, DD, 512 };
    p.BT = WcqT; p.ldb = 2*DD; p.amul = nullptr;
    p.bias = bcq; p.C = cq; p.M = BB; p.N = DD; p.act = 0;
    sgemm_k<<<g_s, blk, 0, stream>>>(p, flag);
    // control
    attn_control_k<<<dim3(BB), blk, 0, stream>>>(cq, wac, bac, words, ctrl, flag);
    // pm = memory0 @ Wm + bm
    p = SP{}; p.nseg = 1;
    p.s[0] = SSeg{ memory0, 0, DD, DD, 0 };
    p.BT = WmT; p.ldb = DD; p.amul = nullptr;
    p.bias = bm; p.C = pm; p.M = BB; p.N = DD; p.act = 0;
    sgemm_k<<<g_s, blk, 0, stream>>>(p, flag);
    // t3b = pm @ Wc1[2D:3D] + bc1
    p = SP{}; p.nseg = 1;
    p.s[0] = SSeg{ pm, 1, DD, DD, 0 };
    p.BT = Wc1t3T; p.ldb = DD; p.amul = nullptr;
    p.bias = bc1; p.C = t3b; p.M = BB; p.N = DD; p.act = 0;
    sgemm_k<<<g_s, blk, 0, stream>>>(p, flag);
    // bias_r
    vbias_k<<<dim3(BB), blk, 0, stream>>>(ctrl, war, bc2, bar, bias_r, flag);
    // u[b,e] = sum_d Wc2[e,d] * (ctrl[b,d]*war[d])
    p = SP{}; p.nseg = 1;
    p.s[0] = SSeg{ ctrl, 1, DD, DD, 0 };
    p.BT = Wc2cv; p.ldb = DD; p.amul = warf;
    p.bias = nullptr; p.C = u_; p.M = BB; p.N = DD; p.act = 0;
    sgemm_k<<<g_s, blk, 0, stream>>>(p, flag);

    // chunked MFMA pipeline: transpose know -> G1 -> G2
    for (int b0 = 0; b0 < BB; b0 += CB){
        int cb = (b0 + CB <= BB) ? CB : (BB - b0);
        int M = cb * HWN;                           // multiple of 128
        dim3 g_tr((HWN + 31)/32, DD/32, cb);
        tr_know<<<g_tr, blk, 0, stream>>>(know, knowT, b0, flag);
        int nR = M / 128;
        int swz = (nR % 8 == 0) ? 1 : 0;            // compact same-XCD c-tile groups
        dim3 gflat(8 * nR);
        g1_mfma<<<gflat, blk, 0, stream>>>(knowT, WkT, bkf, pkT, swz);
        g2_mfma<<<gflat, blk, 0, stream>>>(pkT, Wc1T2, pm, t3b, u_, lpart, b0, swz);
    }

    // deterministic logit assembly, then softmax + read
    reduce_logit_k<<<dim3((BB*HWN + 255)/256), blk, 0, stream>>>(lpart, bias_r, logit);
    softmax_read_k<<<dim3(BB), blk, 0, stream>>>(logit, know, rd, flag);
    // next_mem = [rd, memory0] @ WwcatF^T + bwcat
    p = SP{}; p.nseg = 2;
    p.s[0] = SSeg{ rd,      1, DD, DD, 0 };
    p.s[1] = SSeg{ memory0, 0, DD, DD, 512 };
    p.BT = WwcatF; p.ldb = 2*DD; p.amul = nullptr;
    p.bias = bwcat; p.C = nm; p.M = BB; p.N = DD; p.act = 0;
    sgemm_k<<<g_s, blk, 0, stream>>>(p, flag);
    // out = [control ; next_mem]
    writeout_k<<<dim3(2*NBD/256), blk, 0, stream>>>(ctrl, nm, d_out, flag);
}

// Round 8
// 575.139 us; speedup vs baseline: 1.2496x; 1.1016x over previous
//
#include <hip/hip_runtime.h>
#include <hip/hip_bf16.h>
#include <math.h>

typedef __hip_bfloat16 bf16;
typedef __attribute__((ext_vector_type(8))) short s8v;   // 8 bf16 = 4 VGPR (MFMA A/B frag)
typedef __attribute__((ext_vector_type(4))) float f4v;   // MFMA C/D frag

// B=256, S=32, D=512, HW=196
#define BB 256
#define SS 32
#define DD 512
#define HWN 196
#define AP 40   // LDS row pitch (bf16): 80 B -> conflict-free b128 frag reads

__device__ __forceinline__ float b2f(bf16 x){ return __bfloat162float(x); }
__device__ __forceinline__ bf16 f2b(float x){ return __float2bfloat16(x); }
__device__ __forceinline__ float us2f(unsigned short u){
    union { unsigned int i; float f; } t; t.i = ((unsigned int)u) << 16; return t.f;
}
// dt: 1 = inputs are bf16, 0 = inputs are fp32 (runtime-uniform)
__device__ __forceinline__ float ldin(int dt, const void* p, size_t i){
    return dt ? b2f(((const bf16*)p)[i]) : ((const float*)p)[i];
}

// ---------------- dtype detector ----------------
__global__ void detect_k(const void* q, int* flag){
    __shared__ int cnt;
    if (threadIdx.x == 0) cnt = 0;
    __syncthreads();
    const unsigned short* u = (const unsigned short*)q;
    unsigned short v = u[threadIdx.x * 4];
    int e = (v >> 7) & 0xFF;
    atomicAdd(&cnt, (e >= 100 && e <= 140) ? 1 : 0);
    __syncthreads();
    if (threadIdx.x == 0) *flag = (cnt > 128) ? 1 : 0;
}

// ---------------- fused weight prep (runtime dt; per-dtype alt pointers) ----------------
struct PJob { const void* s; const void* s_b; const void* s2; const void* s2_b;
              bf16* d; int R, C, ldd, kofs, mode, boff; };
struct PrepP { PJob j[11]; const void* war; const void* bk; float* warf; float* bkf; };

__global__ __launch_bounds__(256) void prep_k(PrepP P, const int* __restrict__ flag){
    const int dt = *flag;
    __shared__ float T[32][33];
    int bx = blockIdx.x;
    int ji = 0;
    #pragma unroll
    for (int i = 0; i < 11; ++i) if (bx >= P.j[i].boff) ji = i;
    PJob jb = P.j[ji];
    const void* src  = dt ? jb.s_b  : jb.s;
    const void* src2 = dt ? jb.s2_b : jb.s2;
    int t = bx - jb.boff;
    int tx = threadIdx.x & 31, ty = threadIdx.x >> 5;
    if (jb.mode == 3){
        for (int i = threadIdx.x; i < DD; i += 256){
            P.warf[i] = ldin(dt, P.war, i);
            P.bkf[i]  = ldin(dt, P.bk, i);
        }
        return;
    }
    int nrt = jb.R >> 5;
    int r0 = (t % nrt) << 5, c0 = (t / nrt) << 5;
    if (jb.mode == 2){
        for (int rr = ty; rr < 32; rr += 8)
            jb.d[(size_t)(r0 + rr) * jb.ldd + jb.kofs + c0 + tx] =
                f2b(ldin(dt, src, (size_t)(r0 + rr) * jb.C + c0 + tx));
        return;
    }
    for (int rr = ty; rr < 32; rr += 8){
        float v = ldin(dt, src, (size_t)(r0 + rr) * jb.C + c0 + tx);
        if (jb.mode == 1) v += ldin(dt, src2, (size_t)(r0 + rr) * jb.C + c0 + tx);
        T[rr][tx] = v;
    }
    __syncthreads();
    for (int rr = ty; rr < 32; rr += 8)
        jb.d[(size_t)(c0 + rr) * jb.ldd + jb.kofs + r0 + tx] = f2b(T[tx][rr]);
}

// ---------------- know transpose (per chunk) ----------------
__global__ void tr_know(const void* __restrict__ know, bf16* __restrict__ knowT, int b0,
                        const int* __restrict__ flag){
    const int dt = *flag;
    int bl = blockIdx.z, b = b0 + bl;
    int n0 = blockIdx.x * 32, g0 = blockIdx.y * 32;
    __shared__ float T[32][33];
    int tx = threadIdx.x & 31, ty = threadIdx.x >> 5;
    size_t base = (size_t)b * DD * HWN;
    for (int rr = ty; rr < 32; rr += 8){
        int n = n0 + tx;
        T[rr][tx] = (n < HWN) ? ldin(dt, know, base + (size_t)(g0 + rr) * HWN + n) : 0.f;
    }
    __syncthreads();
    for (int rr = ty; rr < 32; rr += 8){
        int n = n0 + rr;
        if (n < HWN) knowT[((size_t)bl * HWN + n) * DD + g0 + tx] = f2b(T[tx][rr]);
    }
}

// ---- block swizzle: 8 c-tiles of one rt within a 64-id window, same XCD (id%8==rt%8) ----
__device__ __forceinline__ void tile_decode(int idb, int swz, int& rt, int& ct){
    if (swz){ int g = idb >> 6, w = idb & 63; rt = g * 8 + (w & 7); ct = w >> 3; }
    else    { ct = idb & 7; rt = idb >> 3; }
}

// ---------------- MFMA GEMM 1: pkT[M,512] = knowT[M,512] @ WkT^T + bk  (128x64 tile) ----
__global__ __launch_bounds__(256) void g1_mfma(const bf16* __restrict__ A,
                                               const bf16* __restrict__ BT,
                                               const float* __restrict__ bkf,
                                               bf16* __restrict__ C, int swz){
    __shared__ __align__(16) bf16 As[128 * AP];
    __shared__ __align__(16) bf16 Bs[64 * AP];
    const int tid = threadIdx.x, lane = tid & 63, wave = tid >> 6;
    const int q = lane >> 4, mr = lane & 15;
    int rt, ct; tile_decode(blockIdx.x, swz, rt, ct);
    const int r0 = rt * 128, c0 = ct * 64;
    f4v acc[2][4];
    #pragma unroll
    for (int t = 0; t < 2; ++t)
        #pragma unroll
        for (int j = 0; j < 4; ++j){ f4v z = {0.f,0.f,0.f,0.f}; acc[t][j] = z; }
    for (int k0 = 0; k0 < DD; k0 += 32){
        #pragma unroll
        for (int cc = 0; cc < 2; ++cc){
            int c = tid + cc * 256;
            int row = c >> 2, ko = (c & 3) * 8;
            *(float4*)&As[row * AP + ko] =
                *(const float4*)(A + (size_t)(r0 + row) * DD + k0 + ko);
        }
        {
            int col = tid >> 2, ko = (tid & 3) * 8;
            *(float4*)&Bs[col * AP + ko] =
                *(const float4*)(BT + (size_t)(c0 + col) * DD + k0 + ko);
        }
        __syncthreads();
        s8v a0 = *(const s8v*)&As[(wave * 32 + mr) * AP + q * 8];
        s8v a1 = *(const s8v*)&As[(wave * 32 + 16 + mr) * AP + q * 8];
        #pragma unroll
        for (int j = 0; j < 4; ++j){
            s8v b = *(const s8v*)&Bs[(j * 16 + mr) * AP + q * 8];
            acc[0][j] = __builtin_amdgcn_mfma_f32_16x16x32_bf16(a0, b, acc[0][j], 0, 0, 0);
            acc[1][j] = __builtin_amdgcn_mfma_f32_16x16x32_bf16(a1, b, acc[1][j], 0, 0, 0);
        }
        __syncthreads();
    }
    #pragma unroll
    for (int t = 0; t < 2; ++t)
        #pragma unroll
        for (int j = 0; j < 4; ++j)
            #pragma unroll
            for (int i = 0; i < 4; ++i){
                int row = r0 + wave * 32 + t * 16 + q * 4 + i;
                int col = c0 + j * 16 + mr;
                C[(size_t)row * DD + col] = f2b(acc[t][j][i] + bkf[col]);
            }
}

// ---------------- MFMA GEMM 2 (per-batch, K=512, pm folded into B) ----------
// For fixed batch b: W_eff[e,d] = pm[b,e]*Wc1[e,d] + Wc1[D+e,d]; h = pk @ W_eff.
// Tiles: 2 r-tiles/batch (rows 0-127, 128-195+pad), 8 c-tiles of 64.
// Deterministic per-ct partials lpart[ct][b*HWN+row] (no atomics).
__global__ __launch_bounds__(256) void g2_mfma(const bf16* __restrict__ Apk,
                                               const bf16* __restrict__ BT,
                                               const float* __restrict__ pmf,
                                               const float* __restrict__ t3b,
                                               const float* __restrict__ uf,
                                               float* __restrict__ lpart,
                                               int b0, int swz){
    __shared__ __align__(16) bf16 As[128 * AP];
    __shared__ __align__(16) bf16 Bs[64 * AP];
    const int tid = threadIdx.x, lane = tid & 63, wave = tid >> 6;
    const int q = lane >> 4, mr = lane & 15;
    int idb = blockIdx.x, u, ct;
    if (swz){ int g = idb >> 6, w = idb & 63; u = g * 8 + (w & 7); ct = w >> 3; }
    else    { u = idb >> 3; ct = idb & 7; }
    const int bl = u >> 1, rt = u & 1;
    const int b = b0 + bl;
    const int c0 = ct * 64, rbase = rt * 128;
    const float* pmb = pmf + (size_t)b * DD;
    f4v acc[2][4];
    #pragma unroll
    for (int t = 0; t < 2; ++t)
        #pragma unroll
        for (int j = 0; j < 4; ++j){ f4v z = {0.f,0.f,0.f,0.f}; acc[t][j] = z; }
    for (int k0 = 0; k0 < DD; k0 += 32){
        #pragma unroll
        for (int cc = 0; cc < 2; ++cc){
            int c = tid + cc * 256;
            int row = c >> 2, ko = (c & 3) * 8;
            int rl = rbase + row;
            float4 v = {0.f, 0.f, 0.f, 0.f};
            if (rl < HWN)
                v = *(const float4*)(Apk + ((size_t)bl * HWN + rl) * DD + k0 + ko);
            *(float4*)&As[row * AP + ko] = v;
        }
        {
            int col = tid >> 2, ko = (tid & 3) * 8;
            const bf16* wrow = BT + (size_t)(c0 + col) * (2 * DD) + k0 + ko;
            union { bf16 h[8]; float4 f; } w1, w2, be;
            w1.f = *(const float4*)wrow;
            w2.f = *(const float4*)(wrow + DD);
            float4 pA = *(const float4*)(pmb + k0 + ko);
            float4 pB = *(const float4*)(pmb + k0 + ko + 4);
            #pragma unroll
            for (int j = 0; j < 4; ++j){
                be.h[j]     = f2b((&pA.x)[j] * b2f(w1.h[j])     + b2f(w2.h[j]));
                be.h[4 + j] = f2b((&pB.x)[j] * b2f(w1.h[4 + j]) + b2f(w2.h[4 + j]));
            }
            *(float4*)&Bs[col * AP + ko] = be.f;
        }
        __syncthreads();
        s8v a0 = *(const s8v*)&As[(wave * 32 + mr) * AP + q * 8];
        s8v a1 = *(const s8v*)&As[(wave * 32 + 16 + mr) * AP + q * 8];
        #pragma unroll
        for (int j = 0; j < 4; ++j){
            s8v b2 = *(const s8v*)&Bs[(j * 16 + mr) * AP + q * 8];
            acc[0][j] = __builtin_amdgcn_mfma_f32_16x16x32_bf16(a0, b2, acc[0][j], 0, 0, 0);
            acc[1][j] = __builtin_amdgcn_mfma_f32_16x16x32_bf16(a1, b2, acc[1][j], 0, 0, 0);
        }
        __syncthreads();
    }
    float part[2][4] = {};
    #pragma unroll
    for (int t = 0; t < 2; ++t)
        #pragma unroll
        for (int j = 0; j < 4; ++j)
            #pragma unroll
            for (int i = 0; i < 4; ++i){
                int rl = rbase + wave * 32 + t * 16 + q * 4 + i;
                if (rl < HWN){
                    int col = c0 + j * 16 + mr;
                    float hv = acc[t][j][i] + t3b[(size_t)b * DD + col];
                    part[t][i] += fmaxf(hv, 0.f) * uf[(size_t)b * DD + col];
                }
            }
    #pragma unroll
    for (int t = 0; t < 2; ++t)
        #pragma unroll
        for (int i = 0; i < 4; ++i){
            float v = part[t][i];
            v += __shfl_xor(v, 1, 16);
            v += __shfl_xor(v, 2, 16);
            v += __shfl_xor(v, 4, 16);
            v += __shfl_xor(v, 8, 16);
            int rl = rbase + wave * 32 + t * 16 + q * 4 + i;
            if (mr == 0 && rl < HWN)
                lpart[(size_t)ct * (BB * HWN) + (size_t)b * HWN + rl] = v;
        }
}

// ---------------- deterministic logit reduce: logit = bias_r + sum_ct lpart ----------------
__global__ void reduce_logit_k(const float* __restrict__ lpart, const float* __restrict__ bias_r,
                               float* __restrict__ logit){
    int i = blockIdx.x * 256 + threadIdx.x;
    const int T = BB * HWN;
    if (i < T){
        float s = bias_r[i / HWN];
        #pragma unroll
        for (int c = 0; c < 8; ++c) s += lpart[(size_t)c * T + i];
        logit[i] = s;
    }
}

// ---------------- fast small GEMM: LDS-free, one 16x16 MFMA tile per wave ----------------
struct SSeg { const void* A; int a_ws, lda, K, koff; };
struct SP {
    SSeg s[2]; int nseg;
    const bf16* BT; int ldb;       // BT[n][k] bf16
    const float* amul;             // optional per-k multiplier on A (seg 0 only)
    const void* bias;              // raw input dtype, may be null
    float* C; int M, N, act;       // act: 0 none, 1 tanh
};

__global__ __launch_bounds__(256) void sgemm_k(SP p, const int* __restrict__ flag){
    const int dt = *flag;
    const int tid = threadIdx.x, lane = tid & 63, w = tid >> 6;
    const int q = lane >> 4, mr = lane & 15;
    const int n0 = blockIdx.x * 16, m0 = blockIdx.y * 64 + w * 16;
    f4v acc = {0.f,0.f,0.f,0.f};
    for (int sg = 0; sg < p.nseg; ++sg){
        const SSeg s = p.s[sg];
        const float* amul = (sg == 0) ? p.amul : nullptr;
        #pragma unroll 4
        for (int k0 = 0; k0 < s.K; k0 += 32){
            const int kk = k0 + q * 8;
            union { bf16 h[8]; s8v v; } a;
            if (s.a_ws || dt == 0){
                const float* Af = (const float*)s.A + (size_t)(m0 + mr) * s.lda + kk;
                float4 f0 = *(const float4*)Af;
                float4 f1 = *(const float4*)(Af + 4);
                float f[8] = {f0.x, f0.y, f0.z, f0.w, f1.x, f1.y, f1.z, f1.w};
                if (amul){
                    #pragma unroll
                    for (int j = 0; j < 8; ++j) f[j] *= amul[kk + j];
                }
                #pragma unroll
                for (int j = 0; j < 8; ++j) a.h[j] = f2b(f[j]);
            } else {
                a.v = *(const s8v*)((const bf16*)s.A + (size_t)(m0 + mr) * s.lda + kk);
                if (amul){
                    #pragma unroll
                    for (int j = 0; j < 8; ++j) a.h[j] = f2b(b2f(a.h[j]) * amul[kk + j]);
                }
            }
            s8v b = *(const s8v*)(p.BT + (size_t)(n0 + mr) * p.ldb + s.koff + kk);
            acc = __builtin_amdgcn_mfma_f32_16x16x32_bf16(a.v, b, acc, 0, 0, 0);
        }
    }
    #pragma unroll
    for (int i = 0; i < 4; ++i){
        int row = m0 + q * 4 + i, col = n0 + mr;
        float v = acc[i] + (p.bias ? ldin(dt, p.bias, col) : 0.f);
        if (p.act == 1) v = tanhf(v);
        p.C[(size_t)row * p.N + col] = v;
    }
}

// ---------------- control attention ----------------
__global__ __launch_bounds__(256) void attn_control_k(const float* __restrict__ cq,
                                                      const void* __restrict__ wac,
                                                      const void* __restrict__ bac,
                                                      const void* __restrict__ words,
                                                      float* __restrict__ control,
                                                      const int* __restrict__ flag){
    const int dt = *flag;
    const int b = blockIdx.x, tid = threadIdx.x;
    __shared__ float cw[DD];
    __shared__ float lg[SS];
    __shared__ float es[SS];
    for (int d = tid; d < DD; d += 256) cw[d] = cq[(size_t)b*DD + d] * ldin(dt, wac, d);
    __syncthreads();
    int s = tid >> 3, l8 = tid & 7;
    float p = 0.f;
    for (int d = l8; d < DD; d += 8) p += cw[d] * ldin(dt, words, ((size_t)b*SS + s)*DD + d);
    for (int off = 4; off; off >>= 1) p += __shfl_down(p, off, 8);
    if (l8 == 0) lg[s] = p + ldin(dt, bac, 0);
    __syncthreads();
    if (tid == 0){
        float mx = -INFINITY;
        for (int i = 0; i < SS; ++i) mx = fmaxf(mx, lg[i]);
        float sm = 0.f;
        for (int i = 0; i < SS; ++i){ es[i] = expf(lg[i] - mx); sm += es[i]; }
        float inv = 1.f / sm;
        for (int i = 0; i < SS; ++i) es[i] *= inv;
    }
    __syncthreads();
    for (int d = tid; d < DD; d += 256){
        float c = 0.f;
        #pragma unroll 8
        for (int s2 = 0; s2 < SS; ++s2) c += es[s2] * ldin(dt, words, ((size_t)b*SS + s2)*DD + d);
        control[(size_t)b*DD + d] = c;
    }
}

// ---------------- bias_r = dot(bc2, control*war) + bar ----------------
__global__ __launch_bounds__(256) void vbias_k(const float* __restrict__ control,
                                               const void* __restrict__ war,
                                               const void* __restrict__ bc2,
                                               const void* __restrict__ bar,
                                               float* __restrict__ bias_r,
                                               const int* __restrict__ flag){
    const int dt = *flag;
    const int b = blockIdx.x, tid = threadIdx.x;
    __shared__ float red[256];
    float p = 0.f;
    for (int d = tid; d < DD; d += 256)
        p += ldin(dt, bc2, d) * control[(size_t)b*DD + d] * ldin(dt, war, d);
    red[tid] = p; __syncthreads();
    for (int off = 128; off; off >>= 1){ if (tid < off) red[tid] += red[tid + off]; __syncthreads(); }
    if (tid == 0) bias_r[b] = red[0] + ldin(dt, bar, 0);
}

// ---------------- softmax over HW + read ----------------
__global__ __launch_bounds__(256) void softmax_read_k(const float* __restrict__ logit,
                                                      const void* __restrict__ know,
                                                      float* __restrict__ readout,
                                                      const int* __restrict__ flag){
    const int dt = *flag;
    const int b = blockIdx.x, tid = threadIdx.x;
    __shared__ float a[HWN];
    __shared__ float red[256];
    float x = (tid < HWN) ? logit[(size_t)b*HWN + tid] : -INFINITY;
    red[tid] = x; __syncthreads();
    for (int off = 128; off; off >>= 1){ if (tid < off) red[tid] = fmaxf(red[tid], red[tid + off]); __syncthreads(); }
    float mx = red[0]; __syncthreads();
    float e = (tid < HWN) ? expf(x - mx) : 0.f;
    red[tid] = e; __syncthreads();
    for (int off = 128; off; off >>= 1){ if (tid < off) red[tid] += red[tid + off]; __syncthreads(); }
    float inv = 1.f / red[0];
    if (tid < HWN) a[tid] = e * inv;
    __syncthreads();
    for (int d = tid; d < DD; d += 256){
        size_t base = ((size_t)b*DD + d) * HWN;
        float sum = 0.f;
        if (dt){
            const ushort4* k4 = (const ushort4*)((const unsigned short*)know + base);
            #pragma unroll 7
            for (int c = 0; c < HWN/4; ++c){
                ushort4 u4 = k4[c];
                sum += a[4*c+0]*us2f(u4.x) + a[4*c+1]*us2f(u4.y)
                     + a[4*c+2]*us2f(u4.z) + a[4*c+3]*us2f(u4.w);
            }
        } else {
            const float4* k4 = (const float4*)((const float*)know + base);
            #pragma unroll 7
            for (int c = 0; c < HWN/4; ++c){
                float4 f4 = k4[c];
                sum += a[4*c+0]*f4.x + a[4*c+1]*f4.y + a[4*c+2]*f4.z + a[4*c+3]*f4.w;
            }
        }
        readout[(size_t)b*DD + d] = sum;
    }
}

// ---------------- final write ----------------
__global__ void writeout_k(const float* __restrict__ control, const float* __restrict__ nm,
                           void* __restrict__ out, const int* __restrict__ flag){
    const int dt = *flag;
    int i = blockIdx.x * 256 + threadIdx.x;
    const int NBD = BB * DD;
    float v;
    if (i < NBD) v = control[i];
    else if (i < 2*NBD) v = nm[i - NBD];
    else return;
    if (dt) ((bf16*)out)[i] = f2b(v);
    else    ((float*)out)[i] = v;
}

extern "C" void kernel_launch(void* const* d_in, const int* in_sizes, int n_in,
                              void* d_out, int out_size, void* d_ws, size_t ws_size,
                              hipStream_t stream){
    const void* words    = d_in[0];
    const void* question = d_in[1];
    const void* know     = d_in[2];
    const void* control0 = d_in[3];
    const void* memory0  = d_in[4];
    const void* Wsc = d_in[5];   const void* bsc = d_in[6];
    const void* Wp  = d_in[7];   const void* bp  = d_in[8];
    const void* Wcq = d_in[9];   const void* bcq = d_in[10];
    const void* wac = d_in[11];  const void* bac = d_in[12];
    const void* Wm  = d_in[13];  const void* bm  = d_in[14];
    const void* Wk  = d_in[15];  const void* bk  = d_in[16];
    const void* Wc1 = d_in[17];  const void* bc1 = d_in[18];
    const void* Wc2 = d_in[19];  const void* bc2 = d_in[20];
    const void* war = d_in[21];  const void* bar = d_in[22];
    // d_in[23..26] dead: softmax over singleton axis == 1 => attn_mem == memory0
    const void* Wwcat = d_in[27]; const void* bwcat = d_in[28];

    int* flag = (int*)d_ws;
    float* F = ((float*)d_ws) + 16;
    const int NBD = BB * DD;
    float* q_   = F;
    float* pa   = F + 1*NBD;
    float* cq   = F + 2*NBD;
    float* ctrl = F + 3*NBD;
    float* pm   = F + 4*NBD;
    float* t3b  = F + 5*NBD;
    float* u_   = F + 6*NBD;
    float* rd   = F + 7*NBD;
    float* nm   = F + 8*NBD;
    float* bias_r = F + 9*NBD;                  // [B]
    float* logit  = bias_r + BB;                // [B*HW]
    float* warf   = logit + BB*HWN;             // [D]
    float* bkf    = warf + DD;                  // [D]
    float* lpart  = bkf + DD;                   // [8][B*HW]
    size_t off_f = 16 + 9*(size_t)NBD + BB + (size_t)BB*HWN + 2*DD + 8*(size_t)BB*HWN;
    size_t byte_off = (off_f * 4 + 255) & ~(size_t)255;
    bf16* WB = (bf16*)((char*)d_ws + byte_off);
    bf16* WscT   = WB;                          // [512][1024]
    bf16* WcqT   = WscT  + (size_t)DD*2*DD;     // [512][1024]
    bf16* Wc1T2  = WcqT  + (size_t)DD*2*DD;     // [512][1024]
    bf16* WwcatF = Wc1T2 + (size_t)DD*2*DD;     // [512][1024]
    bf16* WpT    = WwcatF+ (size_t)DD*2*DD;     // [512][512]
    bf16* WmT    = WpT   + (size_t)DD*DD;
    bf16* Wc1t3T = WmT   + (size_t)DD*DD;
    bf16* WkT    = Wc1t3T+ (size_t)DD*DD;
    bf16* Wc2cv  = WkT   + (size_t)DD*DD;
    size_t big_off = (byte_off + ((size_t)DD*2*DD*4 + (size_t)DD*DD*5) * sizeof(bf16) + 255) & ~(size_t)255;

    size_t per_batch = (size_t)HWN * DD * sizeof(bf16) * 2;     // knowT + pkT
    size_t avail = (ws_size > big_off) ? (ws_size - big_off) : 0;
    int CB = (int)(avail / per_batch);
    CB &= ~31;                                                  // multiple of 32
    if (CB > BB) CB = BB;
    if (CB < 32) CB = 32;
    bf16* knowT = (bf16*)((char*)d_ws + big_off);               // [CB][196][512]
    bf16* pkT   = knowT + (size_t)CB * HWN * DD;                // [CB][196][512]

    dim3 blk(256);

    detect_k<<<dim3(1), blk, 0, stream>>>(question, flag);

    // ---- fused weight prep (single launch, runtime dt) ----
    {
        PrepP P; int bo = 0;
        auto J = [&](const void* s, const void* sb, const void* s2, const void* s2b,
                     bf16* d, int R, int C, int ldd, int kofs, int mode, int idx){
            int nb = (mode == 3) ? 1 : ((R >> 5) * (C >> 5));
            P.j[idx] = PJob{ s, sb, s2, s2b, d, R, C, ldd, kofs, mode, bo };
            bo += nb;
        };
        const void* Wc1t3_f = (const void*)((const float*)Wc1 + (size_t)2*DD*DD);
        const void* Wc1t3_b = (const void*)((const bf16*) Wc1 + (size_t)2*DD*DD);
        const void* Ww1_f = (const void*)((const float*)Wwcat + (size_t)DD*DD);
        const void* Ww1_b = (const void*)((const bf16*) Wwcat + (size_t)DD*DD);
        const void* Ww2_f = (const void*)((const float*)Wwcat + (size_t)2*DD*DD);
        const void* Ww2_b = (const void*)((const bf16*) Wwcat + (size_t)2*DD*DD);
        J(Wsc,   Wsc,   nullptr, nullptr, WscT,   2*DD, DD, 2*DD, 0,   0, 0);
        J(Wp,    Wp,    nullptr, nullptr, WpT,    DD,   DD, DD,   0,   0, 1);
        J(Wcq,   Wcq,   nullptr, nullptr, WcqT,   2*DD, DD, 2*DD, 0,   0, 2);
        J(Wm,    Wm,    nullptr, nullptr, WmT,    DD,   DD, DD,   0,   0, 3);
        J(Wc1,   Wc1,   nullptr, nullptr, Wc1T2,  2*DD, DD, 2*DD, 0,   0, 4);
        J(Wc1t3_f, Wc1t3_b, nullptr, nullptr, Wc1t3T, DD, DD, DD, 0,   0, 5);
        J(Wk,    Wk,    nullptr, nullptr, WkT,    DD,   DD, DD,   0,   0, 6);
        J(Wwcat, Wwcat, nullptr, nullptr, WwcatF, DD,   DD, 2*DD, 0,   0, 7);
        J(Ww1_f, Ww1_b, Ww2_f,   Ww2_b,   WwcatF, DD,   DD, 2*DD, 512, 1, 8);
        J(Wc2,   Wc2,   nullptr, nullptr, Wc2cv,  DD,   DD, DD,   0,   2, 9);
        J(nullptr,nullptr,nullptr,nullptr,nullptr,0,    0,  0,    0,   3, 10);
        P.war = war; P.bk = bk; P.warf = warf; P.bkf = bkf;
        prep_k<<<dim3(bo), blk, 0, stream>>>(P, flag);
    }

    dim3 g_s(DD/16, BB/64);     // (32, 4)
    SP p;

    // q = tanh(question @ Wsc + bsc)
    p = SP{}; p.nseg = 1;
    p.s[0] = SSeg{ question, 0, 2*DD, 2*DD, 0 };
    p.BT = WscT; p.ldb = 2*DD; p.amul = nullptr;
    p.bias = bsc; p.C = q_; p.M = BB; p.N = DD; p.act = 1;
    sgemm_k<<<g_s, blk, 0, stream>>>(p, flag);
    // pa = q @ Wp + bp
    p = SP{}; p.nseg = 1;
    p.s[0] = SSeg{ q_, 1, DD, DD, 0 };
    p.BT = WpT; p.ldb = DD; p.amul = nullptr;
    p.bias = bp; p.C = pa; p.M = BB; p.N = DD; p.act = 0;
    sgemm_k<<<g_s, blk, 0, stream>>>(p, flag);
    // cq = [control0, pa] @ Wcq + bcq
    p = SP{}; p.nseg = 2;
    p.s[0] = SSeg{ control0, 0, DD, DD, 0 };
    p.s[1] = SSeg{ pa,       1, DD, DD, 512 };
    p.BT = WcqT; p.ldb = 2*DD; p.amul = nullptr;
    p.bias = bcq; p.C = cq; p.M = BB; p.N = DD; p.act = 0;
    sgemm_k<<<g_s, blk, 0, stream>>>(p, flag);
    // control
    attn_control_k<<<dim3(BB), blk, 0, stream>>>(cq, wac, bac, words, ctrl, flag);
    // pm = memory0 @ Wm + bm
    p = SP{}; p.nseg = 1;
    p.s[0] = SSeg{ memory0, 0, DD, DD, 0 };
    p.BT = WmT; p.ldb = DD; p.amul = nullptr;
    p.bias = bm; p.C = pm; p.M = BB; p.N = DD; p.act = 0;
    sgemm_k<<<g_s, blk, 0, stream>>>(p, flag);
    // t3b = pm @ Wc1[2D:3D] + bc1
    p = SP{}; p.nseg = 1;
    p.s[0] = SSeg{ pm, 1, DD, DD, 0 };
    p.BT = Wc1t3T; p.ldb = DD; p.amul = nullptr;
    p.bias = bc1; p.C = t3b; p.M = BB; p.N = DD; p.act = 0;
    sgemm_k<<<g_s, blk, 0, stream>>>(p, flag);
    // bias_r
    vbias_k<<<dim3(BB), blk, 0, stream>>>(ctrl, war, bc2, bar, bias_r, flag);
    // u[b,e] = sum_d Wc2[e,d] * (ctrl[b,d]*war[d])
    p = SP{}; p.nseg = 1;
    p.s[0] = SSeg{ ctrl, 1, DD, DD, 0 };
    p.BT = Wc2cv; p.ldb = DD; p.amul = warf;
    p.bias = nullptr; p.C = u_; p.M = BB; p.N = DD; p.act = 0;
    sgemm_k<<<g_s, blk, 0, stream>>>(p, flag);

    // chunked MFMA pipeline: transpose know -> G1 -> G2
    for (int b0 = 0; b0 < BB; b0 += CB){
        int cb = (b0 + CB <= BB) ? CB : (BB - b0);
        int M = cb * HWN;                           // multiple of 128 (cb mult of 32)
        dim3 g_tr((HWN + 31)/32, DD/32, cb);
        tr_know<<<g_tr, blk, 0, stream>>>(know, knowT, b0, flag);
        int nR = M / 128;
        int swz1 = (nR % 8 == 0) ? 1 : 0;           // compact same-XCD c-tile groups
        g1_mfma<<<dim3(8 * nR), blk, 0, stream>>>(knowT, WkT, bkf, pkT, swz1);
        int nU = cb * 2;                            // (batch, rtile) units
        int swz2 = (nU % 8 == 0) ? 1 : 0;
        g2_mfma<<<dim3(8 * nU), blk, 0, stream>>>(pkT, Wc1T2, pm, t3b, u_, lpart, b0, swz2);
    }

    // deterministic logit assembly, then softmax + read
    reduce_logit_k<<<dim3((BB*HWN + 255)/256), blk, 0, stream>>>(lpart, bias_r, logit);
    softmax_read_k<<<dim3(BB), blk, 0, stream>>>(logit, know, rd, flag);
    // next_mem = [rd, memory0] @ WwcatF^T + bwcat
    p = SP{}; p.nseg = 2;
    p.s[0] = SSeg{ rd,      1, DD, DD, 0 };
    p.s[1] = SSeg{ memory0, 0, DD, DD, 512 };
    p.BT = WwcatF; p.ldb = 2*DD; p.amul = nullptr;
    p.bias = bwcat; p.C = nm; p.M = BB; p.N = DD; p.act = 0;
    sgemm_k<<<g_s, blk, 0, stream>>>(p, flag);
    // out = [control ; next_mem]
    writeout_k<<<dim3(2*NBD/256), blk, 0, stream>>>(ctrl, nm, d_out, flag);
}